// Round 13
// baseline (240.463 us; speedup 1.0000x reference)
//
#include <hip/hip_runtime.h>

#define TPB 256
#define TPM 192   // k_main block size (3 waves)

// Problem dims
constexpr int B_ = 4096, A_ = 11;
constexpr int R_ = B_ * A_;       // 45056 rows

// ws offsets (floats)
constexpr int M2_O    = 8192;     // 8192   folded through fc3 (32x256)
constexpr int WC_O    = 16384;    // 1024   W_in @ W_pos_top
constexpr int XB_O    = 17408;    // 2048   per-timestep bias
constexpr int B2_O    = 19712;    // 2816   per-agent bias (11x256)
constexpr int WN2L_O  = 22528;    // 4096   Wn2 @ W_line (64x64)
constexpr int MH1_O   = 26624;    // 2048   M @ WfhA1 (32x64)
constexpr int BH1_O   = 28672;    // 704
constexpr int MH2_O   = 29376;    // 2048
constexpr int BH2_O   = 31424;    // 704
constexpr int WFA1_O  = 32768;    // 16384  Wfc3_top @ Wh1 (256x64)
constexpr int WFA2_O  = 49152;    // 16384  Wfc3_top @ Wh2
constexpr int BEYE1_O = 65536;    // 704    Wfc3_eye @ Wh1 (11x64)
constexpr int BEYE2_O = 66240;    // 704
constexpr int BB1_O   = 66944;    // 64     bfc3 @ Wh1
constexpr int BB2_O   = 67008;    // 64
constexpr int AG1_O   = 67584;    // agg1 (R_ x 64)
constexpr int SZ_RH   = R_ * 64;  // 2883584
constexpr int AG2_O   = AG1_O + SZ_RH;

// ================= k_preA: wide parallel folds (unchanged, passing) =================

__global__ __launch_bounds__(TPB) void k_preA(const float* __restrict__ Win,
                                              const float* __restrict__ bin,
                                              const float* __restrict__ Wpos,
                                              const float* __restrict__ bpos,
                                              const float* __restrict__ Wn2,
                                              const float* __restrict__ Wline,
                                              const float* __restrict__ Wfc3,
                                              const float* __restrict__ bfc3,
                                              const float* __restrict__ Wh1,
                                              const float* __restrict__ Wh2,
                                              float* __restrict__ ws) {
    __shared__ float red[8 * 33];
    const int t = threadIdx.x, o8 = t & 31, ks = t >> 5;
    const int bx = blockIdx.x;
    float p = 0.f;
    float base_add = 0.f;
    int out_idx = -1;
    if (bx < 64) {                       // xb[l][j], 2048 outs, K=512 (bin then pe inline)
        int o = bx * 32 + o8, l = o >> 8, j = o & 255;
        const float c0 = -logf(10000.f) / 256.f;
        for (int d = ks * 64; d < ks * 64 + 64; ++d) {
            float a;
            if (d < 256) a = bin[d];
            else {
                int dd = d - 256;
                float freq = expf((float)(dd & ~1) * c0);
                float ang = (float)l * freq;
                a = (dd & 1) ? cosf(ang) : sinf(ang);
            }
            p += a * Wpos[d * 256 + j];
        }
        out_idx = XB_O + o; base_add = bpos[j];
    } else if (bx < 192) {               // Wn2L, 4096 outs
        int o = (bx - 64) * 32 + o8, k = o >> 6, c = o & 63;
        #pragma unroll 8
        for (int d = ks * 32; d < ks * 32 + 32; ++d) p += Wn2[k * 256 + d] * Wline[d * 64 + c];
        out_idx = WN2L_O + o;
    } else if (bx < 704) {               // WfhA1 = Wfc3_top @ Wh1, 16384 outs
        int o = (bx - 192) * 32 + o8, e = o >> 6, c = o & 63;
        #pragma unroll 8
        for (int d = ks * 32; d < ks * 32 + 32; ++d) p += Wfc3[e * 256 + d] * Wh1[d * 64 + c];
        out_idx = WFA1_O + o;
    } else if (bx < 1216) {              // WfhA2 = Wfc3_top @ Wh2
        int o = (bx - 704) * 32 + o8, e = o >> 6, c = o & 63;
        #pragma unroll 8
        for (int d = ks * 32; d < ks * 32 + 32; ++d) p += Wfc3[e * 256 + d] * Wh2[d * 64 + c];
        out_idx = WFA2_O + o;
    } else if (bx < 1238) {              // bEye1 = Wfc3_eye @ Wh1, 704 outs
        int o = (bx - 1216) * 32 + o8, a = o >> 6, c = o & 63;
        #pragma unroll 8
        for (int d = ks * 32; d < ks * 32 + 32; ++d) p += Wfc3[(256 + a) * 256 + d] * Wh1[d * 64 + c];
        out_idx = BEYE1_O + o;
    } else if (bx < 1260) {              // bEye2
        int o = (bx - 1238) * 32 + o8, a = o >> 6, c = o & 63;
        #pragma unroll 8
        for (int d = ks * 32; d < ks * 32 + 32; ++d) p += Wfc3[(256 + a) * 256 + d] * Wh2[d * 64 + c];
        out_idx = BEYE2_O + o;
    } else if (bx < 1262) {              // bb1 = bfc3 @ Wh1, 64 outs
        int c = (bx - 1260) * 32 + o8;
        #pragma unroll 8
        for (int d = ks * 32; d < ks * 32 + 32; ++d) p += bfc3[d] * Wh1[d * 64 + c];
        out_idx = BB1_O + c;
    } else if (bx < 1264) {              // bb2
        int c = (bx - 1262) * 32 + o8;
        #pragma unroll 8
        for (int d = ks * 32; d < ks * 32 + 32; ++d) p += bfc3[d] * Wh2[d * 64 + c];
        out_idx = BB2_O + c;
    } else {                             // Wc = Win @ Wpos_top, 1024 outs
        int o = (bx - 1264) * 32 + o8, i = o >> 8, j = o & 255;
        #pragma unroll 8
        for (int d = ks * 32; d < ks * 32 + 32; ++d) p += Win[i * 256 + d] * Wpos[d * 256 + j];
        out_idx = WC_O + o;
    }
    red[ks * 33 + o8] = p;
    __shared__ float baseS[32];
    if (ks == 0) baseS[o8] = base_add;
    __syncthreads();
    if (t < 32) {
        float s = baseS[t];
        #pragma unroll
        for (int m = 0; m < 8; ++m) s += red[m * 33 + t];
        ws[out_idx - o8 + t] = s;
    }
}

// ================= k_preCD: fused preC+preD — per-block internal M-row/cb =================
// Blocks 0..31: row k — compute M[k][:] in LDS, then M2[k][:], Mh1[k][:], Mh2[k][:].
// Blocks 32..42: agent a — compute cb[:] in LDS, then B2[a][:], bh1[a][:], bh2[a][:].

__global__ __launch_bounds__(TPB) void k_preCD(const float* __restrict__ Wfc2,
                                               const float* __restrict__ bfc2,
                                               const float* __restrict__ Wfc3,
                                               const float* __restrict__ bfc3,
                                               float* __restrict__ ws) {
    __shared__ float rowS[256];
    const int t = threadIdx.x;
    const int bx = blockIdx.x;
    if (bx < 32) {
        const int k = bx, i = k & 3, l = k >> 2;
        const float* WcR = ws + WC_O + i * 256;
        const float* Bcol = Wfc2 + l * 65536 + t;
        float m = 0.f;
        #pragma unroll 8
        for (int d = 0; d < 256; ++d) m += WcR[d] * Bcol[d * 256];
        rowS[t] = m;
        __syncthreads();
        float s = 0.f;
        #pragma unroll 8
        for (int d = 0; d < 256; ++d) s += rowS[d] * Wfc3[d * 256 + t];
        ws[M2_O + k * 256 + t] = s;
        if (t < 128) {
            const int c = t & 63;
            const bool one = t < 64;
            const float* WF = ws + (one ? WFA1_O : WFA2_O);
            float sh = 0.f;
            #pragma unroll 8
            for (int d = 0; d < 256; ++d) sh += rowS[d] * WF[d * 64 + c];
            ws[(one ? MH1_O : MH2_O) + k * 64 + c] = sh;
        }
    } else {
        const int a = bx - 32;
        float cbv = bfc2[t];
        const float* xb = ws + XB_O;
        #pragma unroll 8
        for (int dk = 0; dk < 2048; ++dk) cbv += xb[dk] * Wfc2[dk * 256 + t];
        rowS[t] = cbv;
        __syncthreads();
        float s = bfc3[t] + Wfc3[(256 + a) * 256 + t];
        #pragma unroll 8
        for (int d = 0; d < 256; ++d) s += rowS[d] * Wfc3[d * 256 + t];
        ws[B2_O + a * 256 + t] = s;
        if (t < 128) {
            const int c = t & 63;
            const bool one = t < 64;
            const float* WF = ws + (one ? WFA1_O : WFA2_O);
            float sh = ws[(one ? BB1_O : BB2_O) + c] + ws[(one ? BEYE1_O : BEYE2_O) + a * 64 + c];
            #pragma unroll 8
            for (int d = 0; d < 256; ++d) sh += rowS[d] * WF[d * 64 + c];
            ws[(one ? BH1_O : BH2_O) + a * 64 + c] = sh;
        }
    }
}

// ================= k_main: 22 rows = 2 scenes/block; ≤64-VGPR variant =================
// R12 structure; prefetch-regs removed (direct staging), ftraj B loads in pairs,
// corr to separate dcC (one barrier saved). __launch_bounds__(192,8) caps VGPR at 64.

__global__ __launch_bounds__(TPM, 8) void k_main(const float* __restrict__ in,
                                                 const float* __restrict__ We1g,
                                                 const float* __restrict__ We2g,
                                                 float* ws,
                                                 float* out) {
    __shared__ float inS[22 * 36];     // 3168 B
    __shared__ float buf[22 * 68];     // 5984 B: ft-slices / h / v
    __shared__ float Bs[2048];         // 8192 B
    __shared__ float dcS[242];         // dots
    __shared__ float dcC[242];         // corr
    __shared__ float thrS[2];
    const int t = threadIdx.x;
    const int rg = t >> 4, cg = t & 15;
    const int r0 = rg * 2, c0 = cg * 4;
    const int rowBlk = blockIdx.x * 22;
    const bool act = rg < 11;

    auto stageBs = [&](const float* src) {
        const float4* s = (const float4*)src;
        float4* d = (float4*)Bs;
        d[t] = s[t];
        d[t + 192] = s[t + 192];
        if (t < 128) d[t + 384] = s[t + 384];
    };

    // stage input rows
    for (int o = t; o < 176; o += TPM) {
        int row = o >> 3, c4 = o & 7;
        *(float4*)&inS[row * 36 + c4 * 4] =
            *(const float4*)&in[(size_t)(rowBlk + row) * 32 + c4 * 4];
    }

    // ---- ftraj = in @ M2 + bias2 ----
    float acc[2][16];
    #pragma unroll
    for (int r = 0; r < 2; ++r)
        #pragma unroll
        for (int c = 0; c < 16; ++c) acc[r][c] = 0.f;
    for (int kh = 0; kh < 4; ++kh) {
        if (kh) __syncthreads();         // prior compute's Bs reads done
        stageBs(ws + M2_O + kh * 2048);
        __syncthreads();
        if (act) {
            #pragma unroll
            for (int kq = 0; kq < 2; ++kq) {
                float av[2][4];
                #pragma unroll
                for (int r = 0; r < 2; ++r) {
                    float4 a4 = *(const float4*)&inS[(r0 + r) * 36 + kh * 8 + kq * 4];
                    av[r][0] = a4.x; av[r][1] = a4.y; av[r][2] = a4.z; av[r][3] = a4.w;
                }
                #pragma unroll
                for (int kk = 0; kk < 4; ++kk) {
                    {
                        float4 b0 = *(const float4*)&Bs[(kq * 4 + kk) * 256 + c0];
                        float4 b1 = *(const float4*)&Bs[(kq * 4 + kk) * 256 + c0 + 64];
                        #pragma unroll
                        for (int r = 0; r < 2; ++r) {
                            float a = av[r][kk];
                            acc[r][0] += a * b0.x; acc[r][1] += a * b0.y;
                            acc[r][2] += a * b0.z; acc[r][3] += a * b0.w;
                            acc[r][4] += a * b1.x; acc[r][5] += a * b1.y;
                            acc[r][6] += a * b1.z; acc[r][7] += a * b1.w;
                        }
                    }
                    {
                        float4 b2 = *(const float4*)&Bs[(kq * 4 + kk) * 256 + c0 + 128];
                        float4 b3 = *(const float4*)&Bs[(kq * 4 + kk) * 256 + c0 + 192];
                        #pragma unroll
                        for (int r = 0; r < 2; ++r) {
                            float a = av[r][kk];
                            acc[r][8]  += a * b2.x; acc[r][9]  += a * b2.y;
                            acc[r][10] += a * b2.z; acc[r][11] += a * b2.w;
                            acc[r][12] += a * b3.x; acc[r][13] += a * b3.y;
                            acc[r][14] += a * b3.z; acc[r][15] += a * b3.w;
                        }
                    }
                }
            }
        }
        __syncthreads();
    }
    if (act) {
        #pragma unroll
        for (int r = 0; r < 2; ++r) {
            int row = r0 + r, il = row % 11;
            size_t ob = (size_t)(rowBlk + row) * 576;
            #pragma unroll
            for (int j = 0; j < 4; ++j) {
                float4 b2 = *(const float4*)&ws[B2_O + il * 256 + c0 + j * 64];
                acc[r][j * 4 + 0] += b2.x; acc[r][j * 4 + 1] += b2.y;
                acc[r][j * 4 + 2] += b2.z; acc[r][j * 4 + 3] += b2.w;
                *(float4*)&out[ob + c0 + j * 64] =
                    make_float4(acc[r][j * 4 + 0], acc[r][j * 4 + 1],
                                acc[r][j * 4 + 2], acc[r][j * 4 + 3]);
            }
        }
    }

    // ---- dots via 4 LDS slices; 132 pairs ----
    bool has0 = false;
    int s0_ = 0, i0_ = 0, j0_ = 0;
    if (t < 132) {
        has0 = true; s0_ = t / 66; int p = t % 66; int i = 0;
        while (p >= 11 - i) { p -= 11 - i; ++i; }
        i0_ = i; j0_ = i + p;
    }
    float dacc0 = 0.f;
    #pragma unroll
    for (int sl = 0; sl < 4; ++sl) {
        if (act) {
            #pragma unroll
            for (int r = 0; r < 2; ++r)
                *(float4*)&buf[(r0 + r) * 68 + c0] =
                    make_float4(acc[r][sl * 4 + 0], acc[r][sl * 4 + 1],
                                acc[r][sl * 4 + 2], acc[r][sl * 4 + 3]);
        }
        __syncthreads();
        if (has0) {
            const float* ra = &buf[(s0_ * 11 + i0_) * 68];
            const float* rb = &buf[(s0_ * 11 + j0_) * 68];
            #pragma unroll
            for (int c = 0; c < 16; ++c) {
                float4 a = *(const float4*)&ra[c * 4];
                float4 b = *(const float4*)&rb[c * 4];
                dacc0 += a.x * b.x + a.y * b.y + a.z * b.z + a.w * b.w;
            }
        }
        __syncthreads();
    }
    if (has0) { dcS[s0_ * 121 + i0_ * 11 + j0_] = dacc0;
                dcS[s0_ * 121 + j0_ * 11 + i0_] = dacc0; }
    __syncthreads();

    // ---- corr into dcC (single barrier) + per-scene threshold ----
    {
        float cc0, cc1 = 0.f;
        {
            int idx = t; int si = idx / 121, p = idx % 121, i = p / 11, j = p % 11;
            cc0 = dcS[idx] * rsqrtf(dcS[si * 121 + i * 12] * dcS[si * 121 + j * 12]);
        }
        const bool h2 = (t + TPM < 242);
        if (h2) {
            int idx = t + TPM; int si = idx / 121, p = idx % 121, i = p / 11, j = p % 11;
            cc1 = dcS[idx] * rsqrtf(dcS[si * 121 + i * 12] * dcS[si * 121 + j * 12]);
        }
        dcC[t] = cc0;
        if (h2) dcC[t + TPM] = cc1;
    }
    __syncthreads();
    if (t < 2) {
        float mn = 3.0e38f;
        for (int p = 0; p < 121; ++p) mn = fminf(mn, dcC[t * 121 + p]);
        thrS[t] = (mn < 0.4f) ? 0.4f : ((mn > 0.4f && mn < 0.6f) ? mn + 0.1f : mn + 0.03f);
    }
    __syncthreads();

    // ---- two NMP stages; agg straight to ws ----
    for (int st = 0; st < 2; ++st) {
        const float* bh = ws + (st ? BH2_O : BH1_O);
        const float* We = st ? We2g : We1g;
        stageBs(ws + (st ? MH2_O : MH1_O));
        __syncthreads();
        float hh[2][4];
        #pragma unroll
        for (int r = 0; r < 2; ++r)
            #pragma unroll
            for (int c = 0; c < 4; ++c) hh[r][c] = 0.f;
        if (act) {
            #pragma unroll
            for (int kq = 0; kq < 8; ++kq) {
                float av[2][4];
                #pragma unroll
                for (int r = 0; r < 2; ++r) {
                    float4 a4 = *(const float4*)&inS[(r0 + r) * 36 + kq * 4];
                    av[r][0] = a4.x; av[r][1] = a4.y; av[r][2] = a4.z; av[r][3] = a4.w;
                }
                #pragma unroll
                for (int kk = 0; kk < 4; ++kk) {
                    float4 b = *(const float4*)&Bs[(kq * 4 + kk) * 64 + c0];
                    #pragma unroll
                    for (int r = 0; r < 2; ++r) {
                        float a = av[r][kk];
                        hh[r][0] += a * b.x; hh[r][1] += a * b.y;
                        hh[r][2] += a * b.z; hh[r][3] += a * b.w;
                    }
                }
            }
            #pragma unroll
            for (int r = 0; r < 2; ++r) {
                int il = (r0 + r) % 11;
                float4 b = *(const float4*)&bh[il * 64 + c0];
                *(float4*)&buf[(r0 + r) * 68 + c0] =
                    make_float4(fmaxf(hh[r][0] + b.x, 0.f), fmaxf(hh[r][1] + b.y, 0.f),
                                fmaxf(hh[r][2] + b.z, 0.f), fmaxf(hh[r][3] + b.w, 0.f));
            }
        }
        __syncthreads();
        float uu[2][4], vv[2][4];
        #pragma unroll
        for (int r = 0; r < 2; ++r)
            #pragma unroll
            for (int c = 0; c < 4; ++c) { uu[r][c] = 0.f; vv[r][c] = 0.f; }
        for (int kh = 0; kh < 4; ++kh) {
            if (kh) __syncthreads();
            {   // stage We rows [kh*16,+16) (u) and [64+kh*16,+16) (v)
                const float4* s0 = (const float4*)(We + kh * 1024);
                const float4* s1 = (const float4*)(We + 4096 + kh * 1024);
                float4* d = (float4*)Bs;
                for (int o = t; o < 256; o += TPM) { d[o] = s0[o]; d[256 + o] = s1[o]; }
            }
            __syncthreads();
            if (act) {
                #pragma unroll
                for (int kq = 0; kq < 4; ++kq) {
                    float av[2][4];
                    #pragma unroll
                    for (int r = 0; r < 2; ++r) {
                        float4 a4 = *(const float4*)&buf[(r0 + r) * 68 + kh * 16 + kq * 4];
                        av[r][0] = a4.x; av[r][1] = a4.y; av[r][2] = a4.z; av[r][3] = a4.w;
                    }
                    #pragma unroll
                    for (int kk = 0; kk < 4; ++kk) {
                        float4 bu = *(const float4*)&Bs[(kq * 4 + kk) * 64 + c0];
                        float4 bv = *(const float4*)&Bs[1024 + (kq * 4 + kk) * 64 + c0];
                        #pragma unroll
                        for (int r = 0; r < 2; ++r) {
                            float a = av[r][kk];
                            uu[r][0] += a * bu.x; uu[r][1] += a * bu.y;
                            uu[r][2] += a * bu.z; uu[r][3] += a * bu.w;
                            vv[r][0] += a * bv.x; vv[r][1] += a * bv.y;
                            vv[r][2] += a * bv.z; vv[r][3] += a * bv.w;
                        }
                    }
                }
            }
        }
        __syncthreads();   // buf (h) reads done
        if (act) {   // v over h
            #pragma unroll
            for (int r = 0; r < 2; ++r)
                *(float4*)&buf[(r0 + r) * 68 + c0] =
                    make_float4(vv[r][0], vv[r][1], vv[r][2], vv[r][3]);
        }
        __syncthreads();
        if (act) {
            float* ag = ws + (st ? AG2_O : AG1_O);
            #pragma unroll
            for (int r = 0; r < 2; ++r) {
                int row = r0 + r, s = row / 11, il = row - s * 11;
                float th = thrS[s];
                float t0 = 0.f, t1 = 0.f, t2 = 0.f, t3 = 0.f, cnt = 0.f;
                #pragma unroll
                for (int j = 0; j < 11; ++j) {
                    float4 vj = *(const float4*)&buf[(s * 11 + j) * 68 + c0];
                    if (st == 0) {
                        t0 += fmaxf(uu[r][0] + vj.x, 0.f);
                        t1 += fmaxf(uu[r][1] + vj.y, 0.f);
                        t2 += fmaxf(uu[r][2] + vj.z, 0.f);
                        t3 += fmaxf(uu[r][3] + vj.w, 0.f);
                    } else {
                        float adj = (dcC[s * 121 + il * 11 + j] >= th) ? 1.f : 0.f;
                        t0 += adj * fmaxf(uu[r][0] + vj.x, 0.f);
                        t1 += adj * fmaxf(uu[r][1] + vj.y, 0.f);
                        t2 += adj * fmaxf(uu[r][2] + vj.z, 0.f);
                        t3 += adj * fmaxf(uu[r][3] + vj.w, 0.f);
                        cnt += adj;
                    }
                }
                float inv = (st == 0) ? (1.f / 11.f) : (1.f / (cnt + 1e-6f));
                *(float4*)&ag[(size_t)(rowBlk + row) * 64 + c0] =
                    make_float4(t0 * inv, t1 * inv, t2 * inv, t3 * inv);
            }
        }
        __syncthreads();   // buf (v) reads done before next stage's h-write
    }
}

// ================= k_tail: 32 rows/block; ≤64-VGPR variant =================

__global__ __launch_bounds__(TPB, 8) void k_tail(const float* __restrict__ Wn1,
                                                 const float* __restrict__ ws,
                                                 float* __restrict__ out) {
    __shared__ float aS[32 * 68];    // 8.7 KB
    __shared__ float Bs[2048];       // 8 KB
    const int t = threadIdx.x;
    const int rowBase = blockIdx.x * 32;
    const int tg = t >> 4, tc = t & 15;
    const int r0 = tg * 2, c0 = tc * 4;

    {   // stage agg1
        const float4* s1 = (const float4*)(ws + AG1_O + (size_t)rowBase * 64);
        #pragma unroll
        for (int o = t; o < 512; o += TPB) {
            int row = o >> 4, c4 = o & 15;
            *(float4*)&aS[row * 68 + c4 * 4] = s1[o];
        }
    }
    __syncthreads();

    // ---- inter = agg1 @ Wn1 (K=64) ----
    {
        float acc[2][16];
        #pragma unroll
        for (int r = 0; r < 2; ++r)
            #pragma unroll
            for (int c = 0; c < 16; ++c) acc[r][c] = 0.f;
        for (int kh = 0; kh < 8; ++kh) {
            if (kh) __syncthreads();
            {
                const float4* src = (const float4*)(Wn1 + kh * 2048);
                float4* dst = (float4*)Bs;
                dst[t] = src[t];
                dst[t + 256] = src[t + 256];
            }
            __syncthreads();
            #pragma unroll
            for (int kq = 0; kq < 2; ++kq) {
                float av[2][4];
                #pragma unroll
                for (int r = 0; r < 2; ++r) {
                    float4 a4 = *(const float4*)&aS[(r0 + r) * 68 + kh * 8 + kq * 4];
                    av[r][0] = a4.x; av[r][1] = a4.y; av[r][2] = a4.z; av[r][3] = a4.w;
                }
                #pragma unroll
                for (int kk = 0; kk < 4; ++kk) {
                    {
                        float4 b0 = *(const float4*)&Bs[(kq * 4 + kk) * 256 + c0];
                        float4 b1 = *(const float4*)&Bs[(kq * 4 + kk) * 256 + c0 + 64];
                        #pragma unroll
                        for (int r = 0; r < 2; ++r) {
                            float a = av[r][kk];
                            acc[r][0] += a * b0.x; acc[r][1] += a * b0.y;
                            acc[r][2] += a * b0.z; acc[r][3] += a * b0.w;
                            acc[r][4] += a * b1.x; acc[r][5] += a * b1.y;
                            acc[r][6] += a * b1.z; acc[r][7] += a * b1.w;
                        }
                    }
                    {
                        float4 b2 = *(const float4*)&Bs[(kq * 4 + kk) * 256 + c0 + 128];
                        float4 b3 = *(const float4*)&Bs[(kq * 4 + kk) * 256 + c0 + 192];
                        #pragma unroll
                        for (int r = 0; r < 2; ++r) {
                            float a = av[r][kk];
                            acc[r][8]  += a * b2.x; acc[r][9]  += a * b2.y;
                            acc[r][10] += a * b2.z; acc[r][11] += a * b2.w;
                            acc[r][12] += a * b3.x; acc[r][13] += a * b3.y;
                            acc[r][14] += a * b3.z; acc[r][15] += a * b3.w;
                        }
                    }
                }
            }
        }
        #pragma unroll
        for (int r = 0; r < 2; ++r) {
            size_t ob = (size_t)(rowBase + r0 + r) * 576 + 256;
            #pragma unroll
            for (int j = 0; j < 4; ++j)
                *(float4*)&out[ob + c0 + j * 64] =
                    make_float4(acc[r][j * 4 + 0], acc[r][j * 4 + 1],
                                acc[r][j * 4 + 2], acc[r][j * 4 + 3]);
        }
    }

    __syncthreads();
    {   // restage aS with agg2
        const float4* s2 = (const float4*)(ws + AG2_O + (size_t)rowBase * 64);
        #pragma unroll
        for (int o = t; o < 512; o += TPB) {
            int row = o >> 4, c4 = o & 15;
            *(float4*)&aS[row * 68 + c4 * 4] = s2[o];
        }
    }
    // ---- feat = agg2 @ Wn2L (K=64) ----
    {
        float fa[2][4];
        #pragma unroll
        for (int r = 0; r < 2; ++r)
            #pragma unroll
            for (int c = 0; c < 4; ++c) fa[r][c] = 0.f;
        for (int kh = 0; kh < 2; ++kh) {
            __syncthreads();
            {
                const float4* src = (const float4*)(ws + WN2L_O + kh * 2048);
                float4* dst = (float4*)Bs;
                dst[t] = src[t];
                dst[t + 256] = src[t + 256];
            }
            __syncthreads();
            #pragma unroll
            for (int kq = 0; kq < 8; ++kq) {
                float av[2][4];
                #pragma unroll
                for (int r = 0; r < 2; ++r) {
                    float4 a4 = *(const float4*)&aS[(r0 + r) * 68 + kh * 32 + kq * 4];
                    av[r][0] = a4.x; av[r][1] = a4.y; av[r][2] = a4.z; av[r][3] = a4.w;
                }
                #pragma unroll
                for (int kk = 0; kk < 4; ++kk) {
                    float4 b = *(const float4*)&Bs[(kq * 4 + kk) * 64 + c0];
                    #pragma unroll
                    for (int r = 0; r < 2; ++r) {
                        float a = av[r][kk];
                        fa[r][0] += a * b.x; fa[r][1] += a * b.y;
                        fa[r][2] += a * b.z; fa[r][3] += a * b.w;
                    }
                }
            }
        }
        #pragma unroll
        for (int r = 0; r < 2; ++r)
            *(float4*)&out[(size_t)(rowBase + r0 + r) * 576 + 512 + c0] =
                make_float4(fa[r][0], fa[r][1], fa[r][2], fa[r][3]);
    }
}

extern "C" void kernel_launch(void* const* d_in, const int* in_sizes, int n_in,
                              void* d_out, int out_size, void* d_ws, size_t ws_size,
                              hipStream_t stream) {
    (void)in_sizes; (void)n_in; (void)out_size; (void)ws_size;
    const float* in     = (const float*)d_in[0];
    const float* W_in   = (const float*)d_in[1];
    const float* b_in   = (const float*)d_in[2];
    const float* W_pos  = (const float*)d_in[3];
    const float* b_pos  = (const float*)d_in[4];
    const float* W_fc2  = (const float*)d_in[5];
    const float* b_fc2  = (const float*)d_in[6];
    const float* W_fc3  = (const float*)d_in[7];
    const float* b_fc3  = (const float*)d_in[8];
    const float* Wh1    = (const float*)d_in[9];
    const float* We1    = (const float*)d_in[10];
    const float* Wn1    = (const float*)d_in[11];
    const float* Wh2    = (const float*)d_in[12];
    const float* We2    = (const float*)d_in[13];
    const float* Wn2    = (const float*)d_in[14];
    const float* W_line = (const float*)d_in[15];
    float* out = (float*)d_out;
    float* ws  = (float*)d_ws;

    k_preA<<<1296, TPB, 0, stream>>>(W_in, b_in, W_pos, b_pos, Wn2, W_line,
                                     W_fc3, b_fc3, Wh1, Wh2, ws);
    k_preCD<<<43, TPB, 0, stream>>>(W_fc2, b_fc2, W_fc3, b_fc3, ws);
    k_main<<<R_ / 22, TPM, 0, stream>>>(in, We1, We2, ws, out);
    k_tail<<<R_ / 32, TPB, 0, stream>>>(Wn1, ws, out);
}

// Round 14
// 154.751 us; speedup vs baseline: 1.5539x; 1.5539x over previous
//
#include <hip/hip_runtime.h>

#define TPB 256
#define TPM 192   // k_main block size (3 waves)

// Problem dims
constexpr int B_ = 4096, A_ = 11;
constexpr int R_ = B_ * A_;       // 45056 rows

// ws offsets (floats)
constexpr int M_O     = 0;        // 8192   folded through fc2 (32x256)
constexpr int M2_O    = 8192;     // 8192   folded through fc3 (32x256)
constexpr int WC_O    = 16384;    // 1024   W_in @ W_pos_top
constexpr int XB_O    = 17408;    // 2048   per-timestep bias
constexpr int CB_O    = 19456;    // 256
constexpr int B2_O    = 19712;    // 2816   per-agent bias (11x256)
constexpr int WN2L_O  = 22528;    // 4096   Wn2 @ W_line (64x64)
constexpr int MH1_O   = 26624;    // 2048   M @ WfhA1 (32x64)
constexpr int BH1_O   = 28672;    // 704
constexpr int MH2_O   = 29376;    // 2048
constexpr int BH2_O   = 31424;    // 704
constexpr int WFA1_O  = 32768;    // 16384  Wfc3_top @ Wh1 (256x64)
constexpr int WFA2_O  = 49152;    // 16384  Wfc3_top @ Wh2
constexpr int BEYE1_O = 65536;    // 704    Wfc3_eye @ Wh1 (11x64)
constexpr int BEYE2_O = 66240;    // 704
constexpr int BB1_O   = 66944;    // 64     bfc3 @ Wh1
constexpr int BB2_O   = 67008;    // 64
constexpr int AG1_O   = 67584;    // agg1 (R_ x 64)
constexpr int SZ_RH   = R_ * 64;  // 2883584
constexpr int AG2_O   = AG1_O + SZ_RH;

// ================= pre kernels: wide split-K folds (R12 verbatim, passing) =================

__global__ __launch_bounds__(TPB) void k_preA(const float* __restrict__ Win,
                                              const float* __restrict__ bin,
                                              const float* __restrict__ Wpos,
                                              const float* __restrict__ bpos,
                                              const float* __restrict__ Wn2,
                                              const float* __restrict__ Wline,
                                              const float* __restrict__ Wfc3,
                                              const float* __restrict__ bfc3,
                                              const float* __restrict__ Wh1,
                                              const float* __restrict__ Wh2,
                                              float* __restrict__ ws) {
    __shared__ float red[8 * 33];
    const int t = threadIdx.x, o8 = t & 31, ks = t >> 5;
    const int bx = blockIdx.x;
    float p = 0.f;
    float base_add = 0.f;
    int out_idx = -1;
    if (bx < 64) {                       // xb[l][j], 2048 outs, K=512 (bin then pe inline)
        int o = bx * 32 + o8, l = o >> 8, j = o & 255;
        const float c0 = -logf(10000.f) / 256.f;
        for (int d = ks * 64; d < ks * 64 + 64; ++d) {
            float a;
            if (d < 256) a = bin[d];
            else {
                int dd = d - 256;
                float freq = expf((float)(dd & ~1) * c0);
                float ang = (float)l * freq;
                a = (dd & 1) ? cosf(ang) : sinf(ang);
            }
            p += a * Wpos[d * 256 + j];
        }
        out_idx = XB_O + o; base_add = bpos[j];
    } else if (bx < 192) {               // Wn2L, 4096 outs
        int o = (bx - 64) * 32 + o8, k = o >> 6, c = o & 63;
        #pragma unroll 8
        for (int d = ks * 32; d < ks * 32 + 32; ++d) p += Wn2[k * 256 + d] * Wline[d * 64 + c];
        out_idx = WN2L_O + o;
    } else if (bx < 704) {               // WfhA1 = Wfc3_top @ Wh1, 16384 outs
        int o = (bx - 192) * 32 + o8, e = o >> 6, c = o & 63;
        #pragma unroll 8
        for (int d = ks * 32; d < ks * 32 + 32; ++d) p += Wfc3[e * 256 + d] * Wh1[d * 64 + c];
        out_idx = WFA1_O + o;
    } else if (bx < 1216) {              // WfhA2 = Wfc3_top @ Wh2
        int o = (bx - 704) * 32 + o8, e = o >> 6, c = o & 63;
        #pragma unroll 8
        for (int d = ks * 32; d < ks * 32 + 32; ++d) p += Wfc3[e * 256 + d] * Wh2[d * 64 + c];
        out_idx = WFA2_O + o;
    } else if (bx < 1238) {              // bEye1 = Wfc3_eye @ Wh1, 704 outs
        int o = (bx - 1216) * 32 + o8, a = o >> 6, c = o & 63;
        #pragma unroll 8
        for (int d = ks * 32; d < ks * 32 + 32; ++d) p += Wfc3[(256 + a) * 256 + d] * Wh1[d * 64 + c];
        out_idx = BEYE1_O + o;
    } else if (bx < 1260) {              // bEye2
        int o = (bx - 1238) * 32 + o8, a = o >> 6, c = o & 63;
        #pragma unroll 8
        for (int d = ks * 32; d < ks * 32 + 32; ++d) p += Wfc3[(256 + a) * 256 + d] * Wh2[d * 64 + c];
        out_idx = BEYE2_O + o;
    } else if (bx < 1262) {              // bb1 = bfc3 @ Wh1, 64 outs
        int c = (bx - 1260) * 32 + o8;
        #pragma unroll 8
        for (int d = ks * 32; d < ks * 32 + 32; ++d) p += bfc3[d] * Wh1[d * 64 + c];
        out_idx = BB1_O + c;
    } else if (bx < 1264) {              // bb2
        int c = (bx - 1262) * 32 + o8;
        #pragma unroll 8
        for (int d = ks * 32; d < ks * 32 + 32; ++d) p += bfc3[d] * Wh2[d * 64 + c];
        out_idx = BB2_O + c;
    } else {                             // Wc = Win @ Wpos_top, 1024 outs
        int o = (bx - 1264) * 32 + o8, i = o >> 8, j = o & 255;
        #pragma unroll 8
        for (int d = ks * 32; d < ks * 32 + 32; ++d) p += Win[i * 256 + d] * Wpos[d * 256 + j];
        out_idx = WC_O + o;
    }
    red[ks * 33 + o8] = p;
    __shared__ float baseS[32];
    if (ks == 0) baseS[o8] = base_add;
    __syncthreads();
    if (t < 32) {
        float s = baseS[t];
        #pragma unroll
        for (int m = 0; m < 8; ++m) s += red[m * 33 + t];
        ws[out_idx - o8 + t] = s;
    }
}

__global__ __launch_bounds__(TPB) void k_preC(const float* __restrict__ Wfc2,
                                              const float* __restrict__ bfc2,
                                              float* __restrict__ ws) {
    __shared__ float red[8 * 33];
    const int t = threadIdx.x, o8 = t & 31, ks = t >> 5;
    const int bx = blockIdx.x;
    if (bx < 256) {                      // M[k][j], 8192 outs, K=256; k=(l,i)
        int o = bx * 32 + o8, k = o >> 8, j = o & 255;
        int l = k >> 2, i = k & 3;
        const float* Ar = ws + WC_O + i * 256;
        const float* Br = Wfc2 + l * 65536 + j;
        float p = 0.f;
        #pragma unroll 8
        for (int d = ks * 32; d < ks * 32 + 32; ++d) p += Ar[d] * Br[d * 256];
        red[ks * 33 + o8] = p;
        __syncthreads();
        if (t < 32) {
            float s = 0.f;
            #pragma unroll
            for (int m = 0; m < 8; ++m) s += red[m * 33 + t];
            ws[M_O + bx * 32 + t] = s;
        }
    } else {                             // cb[j], 256 outs, K=2048
        int j = (bx - 256) * 32 + o8;
        const float* Ar = ws + XB_O;
        float p = 0.f;
        #pragma unroll 4
        for (int dk = ks * 256; dk < ks * 256 + 256; ++dk) p += Ar[dk] * Wfc2[dk * 256 + j];
        red[ks * 33 + o8] = p;
        __syncthreads();
        if (t < 32) {
            int jj = (bx - 256) * 32 + t;
            float s = bfc2[jj];
            #pragma unroll
            for (int m = 0; m < 8; ++m) s += red[m * 33 + t];
            ws[CB_O + jj] = s;
        }
    }
}

__global__ __launch_bounds__(TPB) void k_preD(const float* __restrict__ Wfc3,
                                              const float* __restrict__ bfc3,
                                              float* __restrict__ ws) {
    __shared__ float red[8 * 33];
    const int t = threadIdx.x, o8 = t & 31, ks = t >> 5;
    const int bx = blockIdx.x;
    float p = 0.f;
    int out_base = -1;
    int oo32 = 0;
    if (bx < 256) {                      // M2 = M @ Wfc3_top, 8192 outs
        int o = bx * 32 + o8, k = o >> 8, j = o & 255;
        const float* Ar = ws + M_O + k * 256;
        #pragma unroll 8
        for (int d = ks * 32; d < ks * 32 + 32; ++d) p += Ar[d] * Wfc3[d * 256 + j];
        out_base = M2_O; oo32 = bx * 32;
    } else if (bx < 344) {               // bias2[a][j], 2816 outs
        int o = (bx - 256) * 32 + o8, j = o & 255;
        const float* Ar = ws + CB_O;
        #pragma unroll 8
        for (int d = ks * 32; d < ks * 32 + 32; ++d) p += Ar[d] * Wfc3[d * 256 + j];
        out_base = B2_O; oo32 = (bx - 256) * 32;
    } else if (bx < 408) {               // Mh1 = M @ WfhA1, 2048 outs
        int o = (bx - 344) * 32 + o8, k = o >> 6, c = o & 63;
        const float* Ar = ws + M_O + k * 256;
        const float* Br = ws + WFA1_O;
        #pragma unroll 8
        for (int d = ks * 32; d < ks * 32 + 32; ++d) p += Ar[d] * Br[d * 64 + c];
        out_base = MH1_O; oo32 = (bx - 344) * 32;
    } else if (bx < 472) {               // Mh2 = M @ WfhA2
        int o = (bx - 408) * 32 + o8, k = o >> 6, c = o & 63;
        const float* Ar = ws + M_O + k * 256;
        const float* Br = ws + WFA2_O;
        #pragma unroll 8
        for (int d = ks * 32; d < ks * 32 + 32; ++d) p += Ar[d] * Br[d * 64 + c];
        out_base = MH2_O; oo32 = (bx - 408) * 32;
    } else if (bx < 494) {               // bh1 = cb@WfhA1 + bEye1 + bb1, 704 outs
        int o = (bx - 472) * 32 + o8, c = o & 63;
        const float* Ar = ws + CB_O;
        const float* Br = ws + WFA1_O;
        #pragma unroll 8
        for (int d = ks * 32; d < ks * 32 + 32; ++d) p += Ar[d] * Br[d * 64 + c];
        out_base = BH1_O; oo32 = (bx - 472) * 32;
    } else {                             // bh2
        int o = (bx - 494) * 32 + o8, c = o & 63;
        const float* Ar = ws + CB_O;
        const float* Br = ws + WFA2_O;
        #pragma unroll 8
        for (int d = ks * 32; d < ks * 32 + 32; ++d) p += Ar[d] * Br[d * 64 + c];
        out_base = BH2_O; oo32 = (bx - 494) * 32;
    }
    red[ks * 33 + o8] = p;
    __syncthreads();
    if (t < 32) {
        int oo = oo32 + t;
        float s;
        if (out_base == B2_O) {
            int aa = oo >> 8, jj = oo & 255;
            s = bfc3[jj] + Wfc3[(256 + aa) * 256 + jj];
        } else if (out_base == BH1_O) {
            int aa = oo >> 6, cc = oo & 63;
            s = ws[BB1_O + cc] + ws[BEYE1_O + aa * 64 + cc];
        } else if (out_base == BH2_O) {
            int aa = oo >> 6, cc = oo & 63;
            s = ws[BB2_O + cc] + ws[BEYE2_O + aa * 64 + cc];
        } else s = 0.f;
        #pragma unroll
        for (int m = 0; m < 8; ++m) s += red[m * 33 + t];
        ws[out_base + oo] = s;
    }
}

// ================= k_main: 22 rows = 2 scenes/block, prefetched (R12 verbatim) =================

__global__ __launch_bounds__(TPM) void k_main(const float* __restrict__ in,
                                              const float* __restrict__ We1g,
                                              const float* __restrict__ We2g,
                                              float* ws,
                                              float* out) {
    __shared__ float inS[22 * 36];     // 3168 B
    __shared__ float buf[22 * 68];     // 5984 B: ft-slices / h / v
    __shared__ float Bs[2048];         // 8192 B
    __shared__ float dcS[242];
    __shared__ float thrS[2];
    const int t = threadIdx.x;
    const int rg = t >> 4, cg = t & 15;
    const int r0 = rg * 2, c0 = cg * 4;
    const int rowBlk = blockIdx.x * 22;
    const bool act = rg < 11;

    float4 pf0, pf1, pf2;
    auto pfLoad = [&](const float4* lo, const float4* hi) {
        pf0 = lo[t];
        pf1 = (t < 64) ? lo[t + 192] : hi[t - 64];
        if (t < 128) pf2 = hi[t + 128];
    };
    auto pfStore = [&]() {
        float4* d = (float4*)Bs;
        d[t] = pf0; d[t + 192] = pf1;
        if (t < 128) d[t + 384] = pf2;
    };

    pfLoad((const float4*)(ws + M2_O), (const float4*)(ws + M2_O) + 256);
    for (int o = t; o < 176; o += TPM) {
        int row = o >> 3, c4 = o & 7;
        *(float4*)&inS[row * 36 + c4 * 4] =
            *(const float4*)&in[(size_t)(rowBlk + row) * 32 + c4 * 4];
    }
    __syncthreads();

    // ---- ftraj = in @ M2 + bias2 ----
    float acc[2][16];
    #pragma unroll
    for (int r = 0; r < 2; ++r)
        #pragma unroll
        for (int c = 0; c < 16; ++c) acc[r][c] = 0.f;
    for (int kh = 0; kh < 4; ++kh) {
        pfStore();
        if (kh < 3) pfLoad((const float4*)(ws + M2_O) + (kh + 1) * 512,
                           (const float4*)(ws + M2_O) + (kh + 1) * 512 + 256);
        else        pfLoad((const float4*)(ws + MH1_O), (const float4*)(ws + MH1_O) + 256);
        __syncthreads();
        if (act) {
            #pragma unroll
            for (int kq = 0; kq < 2; ++kq) {
                float av[2][4];
                #pragma unroll
                for (int r = 0; r < 2; ++r) {
                    float4 a4 = *(const float4*)&inS[(r0 + r) * 36 + kh * 8 + kq * 4];
                    av[r][0] = a4.x; av[r][1] = a4.y; av[r][2] = a4.z; av[r][3] = a4.w;
                }
                #pragma unroll
                for (int kk = 0; kk < 4; ++kk) {
                    float4 b[4];
                    #pragma unroll
                    for (int j = 0; j < 4; ++j)
                        b[j] = *(const float4*)&Bs[(kq * 4 + kk) * 256 + c0 + j * 64];
                    #pragma unroll
                    for (int r = 0; r < 2; ++r) {
                        float a = av[r][kk];
                        #pragma unroll
                        for (int j = 0; j < 4; ++j) {
                            acc[r][j * 4 + 0] += a * b[j].x;
                            acc[r][j * 4 + 1] += a * b[j].y;
                            acc[r][j * 4 + 2] += a * b[j].z;
                            acc[r][j * 4 + 3] += a * b[j].w;
                        }
                    }
                }
            }
        }
        __syncthreads();
    }
    if (act) {
        #pragma unroll
        for (int r = 0; r < 2; ++r) {
            int row = r0 + r, il = row % 11;
            size_t ob = (size_t)(rowBlk + row) * 576;
            #pragma unroll
            for (int j = 0; j < 4; ++j) {
                float4 b2 = *(const float4*)&ws[B2_O + il * 256 + c0 + j * 64];
                acc[r][j * 4 + 0] += b2.x; acc[r][j * 4 + 1] += b2.y;
                acc[r][j * 4 + 2] += b2.z; acc[r][j * 4 + 3] += b2.w;
                *(float4*)&out[ob + c0 + j * 64] =
                    make_float4(acc[r][j * 4 + 0], acc[r][j * 4 + 1],
                                acc[r][j * 4 + 2], acc[r][j * 4 + 3]);
            }
        }
    }

    // ---- dots via 4 LDS slices; 132 pairs (2 scenes x 66), 1 pair/thread ----
    bool has0 = false;
    int s0_ = 0, i0_ = 0, j0_ = 0;
    if (t < 132) {
        has0 = true; s0_ = t / 66; int p = t % 66; int i = 0;
        while (p >= 11 - i) { p -= 11 - i; ++i; }
        i0_ = i; j0_ = i + p;
    }
    float dacc0 = 0.f;
    #pragma unroll
    for (int sl = 0; sl < 4; ++sl) {
        if (act) {
            #pragma unroll
            for (int r = 0; r < 2; ++r)
                *(float4*)&buf[(r0 + r) * 68 + c0] =
                    make_float4(acc[r][sl * 4 + 0], acc[r][sl * 4 + 1],
                                acc[r][sl * 4 + 2], acc[r][sl * 4 + 3]);
        }
        __syncthreads();
        if (has0) {
            const float* ra = &buf[(s0_ * 11 + i0_) * 68];
            const float* rb = &buf[(s0_ * 11 + j0_) * 68];
            #pragma unroll
            for (int c = 0; c < 16; ++c) {
                float4 a = *(const float4*)&ra[c * 4];
                float4 b = *(const float4*)&rb[c * 4];
                dacc0 += a.x * b.x + a.y * b.y + a.z * b.z + a.w * b.w;
            }
        }
        __syncthreads();
    }
    if (has0) { dcS[s0_ * 121 + i0_ * 11 + j0_] = dacc0;
                dcS[s0_ * 121 + j0_ * 11 + i0_] = dacc0; }
    __syncthreads();

    // ---- corr (in-place, 242 entries) + per-scene threshold ----
    {
        float cc0, cc1 = 0.f;
        {
            int idx = t; int si = idx / 121, p = idx % 121, i = p / 11, j = p % 11;
            cc0 = dcS[idx] * rsqrtf(dcS[si * 121 + i * 12] * dcS[si * 121 + j * 12]);
        }
        if (t + TPM < 242) {
            int idx = t + TPM; int si = idx / 121, p = idx % 121, i = p / 11, j = p % 11;
            cc1 = dcS[idx] * rsqrtf(dcS[si * 121 + i * 12] * dcS[si * 121 + j * 12]);
        }
        __syncthreads();
        dcS[t] = cc0;
        if (t + TPM < 242) dcS[t + TPM] = cc1;
    }
    __syncthreads();
    if (t < 2) {
        float mn = 3.0e38f;
        for (int p = 0; p < 121; ++p) mn = fminf(mn, dcS[t * 121 + p]);
        thrS[t] = (mn < 0.4f) ? 0.4f : ((mn > 0.4f && mn < 0.6f) ? mn + 0.1f : mn + 0.03f);
    }
    __syncthreads();

    // ---- two NMP stages; agg straight to ws ----
    for (int st = 0; st < 2; ++st) {
        const float* bh = ws + (st ? BH2_O : BH1_O);
        const float* We = st ? We2g : We1g;
        pfStore();                                   // Mh
        pfLoad((const float4*)(We), (const float4*)(We + 4096));
        __syncthreads();
        float hh[2][4];
        #pragma unroll
        for (int r = 0; r < 2; ++r)
            #pragma unroll
            for (int c = 0; c < 4; ++c) hh[r][c] = 0.f;
        if (act) {
            #pragma unroll
            for (int kq = 0; kq < 8; ++kq) {
                float av[2][4];
                #pragma unroll
                for (int r = 0; r < 2; ++r) {
                    float4 a4 = *(const float4*)&inS[(r0 + r) * 36 + kq * 4];
                    av[r][0] = a4.x; av[r][1] = a4.y; av[r][2] = a4.z; av[r][3] = a4.w;
                }
                #pragma unroll
                for (int kk = 0; kk < 4; ++kk) {
                    float4 b = *(const float4*)&Bs[(kq * 4 + kk) * 64 + c0];
                    #pragma unroll
                    for (int r = 0; r < 2; ++r) {
                        float a = av[r][kk];
                        hh[r][0] += a * b.x; hh[r][1] += a * b.y;
                        hh[r][2] += a * b.z; hh[r][3] += a * b.w;
                    }
                }
            }
            #pragma unroll
            for (int r = 0; r < 2; ++r) {
                int il = (r0 + r) % 11;
                float4 b = *(const float4*)&bh[il * 64 + c0];
                *(float4*)&buf[(r0 + r) * 68 + c0] =
                    make_float4(fmaxf(hh[r][0] + b.x, 0.f), fmaxf(hh[r][1] + b.y, 0.f),
                                fmaxf(hh[r][2] + b.z, 0.f), fmaxf(hh[r][3] + b.w, 0.f));
            }
        }
        __syncthreads();
        float uu[2][4], vv[2][4];
        #pragma unroll
        for (int r = 0; r < 2; ++r)
            #pragma unroll
            for (int c = 0; c < 4; ++c) { uu[r][c] = 0.f; vv[r][c] = 0.f; }
        for (int kh = 0; kh < 4; ++kh) {
            pfStore();
            if (kh < 3)
                pfLoad((const float4*)(We + (kh + 1) * 1024),
                       (const float4*)(We + 4096 + (kh + 1) * 1024));
            else if (st == 0)
                pfLoad((const float4*)(ws + MH2_O), (const float4*)(ws + MH2_O) + 256);
            __syncthreads();
            if (act) {
                #pragma unroll
                for (int kq = 0; kq < 4; ++kq) {
                    float av[2][4];
                    #pragma unroll
                    for (int r = 0; r < 2; ++r) {
                        float4 a4 = *(const float4*)&buf[(r0 + r) * 68 + kh * 16 + kq * 4];
                        av[r][0] = a4.x; av[r][1] = a4.y; av[r][2] = a4.z; av[r][3] = a4.w;
                    }
                    #pragma unroll
                    for (int kk = 0; kk < 4; ++kk) {
                        float4 bu = *(const float4*)&Bs[(kq * 4 + kk) * 64 + c0];
                        float4 bv = *(const float4*)&Bs[1024 + (kq * 4 + kk) * 64 + c0];
                        #pragma unroll
                        for (int r = 0; r < 2; ++r) {
                            float a = av[r][kk];
                            uu[r][0] += a * bu.x; uu[r][1] += a * bu.y;
                            uu[r][2] += a * bu.z; uu[r][3] += a * bu.w;
                            vv[r][0] += a * bv.x; vv[r][1] += a * bv.y;
                            vv[r][2] += a * bv.z; vv[r][3] += a * bv.w;
                        }
                    }
                }
            }
            __syncthreads();
        }
        if (act) {   // v over h (h dead)
            #pragma unroll
            for (int r = 0; r < 2; ++r)
                *(float4*)&buf[(r0 + r) * 68 + c0] =
                    make_float4(vv[r][0], vv[r][1], vv[r][2], vv[r][3]);
        }
        __syncthreads();
        if (act) {
            float* ag = ws + (st ? AG2_O : AG1_O);
            #pragma unroll
            for (int r = 0; r < 2; ++r) {
                int row = r0 + r, s = row / 11, il = row - s * 11;
                float th = thrS[s];
                float t0 = 0.f, t1 = 0.f, t2 = 0.f, t3 = 0.f, cnt = 0.f;
                #pragma unroll
                for (int j = 0; j < 11; ++j) {
                    float4 vj = *(const float4*)&buf[(s * 11 + j) * 68 + c0];
                    if (st == 0) {
                        t0 += fmaxf(uu[r][0] + vj.x, 0.f);
                        t1 += fmaxf(uu[r][1] + vj.y, 0.f);
                        t2 += fmaxf(uu[r][2] + vj.z, 0.f);
                        t3 += fmaxf(uu[r][3] + vj.w, 0.f);
                    } else {
                        float adj = (dcS[s * 121 + il * 11 + j] >= th) ? 1.f : 0.f;
                        t0 += adj * fmaxf(uu[r][0] + vj.x, 0.f);
                        t1 += adj * fmaxf(uu[r][1] + vj.y, 0.f);
                        t2 += adj * fmaxf(uu[r][2] + vj.z, 0.f);
                        t3 += adj * fmaxf(uu[r][3] + vj.w, 0.f);
                        cnt += adj;
                    }
                }
                float inv = (st == 0) ? (1.f / 11.f) : (1.f / (cnt + 1e-6f));
                *(float4*)&ag[(size_t)(rowBlk + row) * 64 + c0] =
                    make_float4(t0 * inv, t1 * inv, t2 * inv, t3 * inv);
            }
        }
        __syncthreads();   // buf reads done before next stage's h-write
    }
}

// ================= k_tail: 32 rows/block + register prefetch (the one new delta) =================

__global__ __launch_bounds__(TPB) void k_tail(const float* __restrict__ Wn1,
                                              const float* __restrict__ ws,
                                              float* __restrict__ out) {
    __shared__ float aS[32 * 68];    // 8.7 KB
    __shared__ float Bs[2048];       // 8 KB
    const int t = threadIdx.x;
    const int rowBase = blockIdx.x * 32;
    const int tg = t >> 4, tc = t & 15;
    const int r0 = tg * 2, c0 = tc * 4;

    float4 pf0, pf1;
    auto pfLoad = [&](const float* src) {
        const float4* s = (const float4*)src;
        pf0 = s[t]; pf1 = s[t + 256];
    };
    auto pfStore = [&]() {
        float4* d = (float4*)Bs;
        d[t] = pf0; d[t + 256] = pf1;
    };

    pfLoad(Wn1);                      // chunk 0 in flight
    {   // stage agg1
        const float4* s1 = (const float4*)(ws + AG1_O + (size_t)rowBase * 64);
        #pragma unroll
        for (int o = t; o < 512; o += TPB) {
            int row = o >> 4, c4 = o & 15;
            *(float4*)&aS[row * 68 + c4 * 4] = s1[o];
        }
    }

    // ---- inter = agg1 @ Wn1 (K=64), 8 chunks, prefetched ----
    float acc[2][16];
    #pragma unroll
    for (int r = 0; r < 2; ++r)
        #pragma unroll
        for (int c = 0; c < 16; ++c) acc[r][c] = 0.f;
    for (int kh = 0; kh < 8; ++kh) {
        pfStore();
        pfLoad(kh < 7 ? Wn1 + (kh + 1) * 2048 : ws + WN2L_O);
        __syncthreads();          // Bs stores (+ aS stage at kh=0) visible
        #pragma unroll
        for (int kq = 0; kq < 2; ++kq) {
            float av[2][4];
            #pragma unroll
            for (int r = 0; r < 2; ++r) {
                float4 a4 = *(const float4*)&aS[(r0 + r) * 68 + kh * 8 + kq * 4];
                av[r][0] = a4.x; av[r][1] = a4.y; av[r][2] = a4.z; av[r][3] = a4.w;
            }
            #pragma unroll
            for (int kk = 0; kk < 4; ++kk) {
                float4 b[4];
                #pragma unroll
                for (int j = 0; j < 4; ++j)
                    b[j] = *(const float4*)&Bs[(kq * 4 + kk) * 256 + c0 + j * 64];
                #pragma unroll
                for (int r = 0; r < 2; ++r) {
                    float a = av[r][kk];
                    #pragma unroll
                    for (int j = 0; j < 4; ++j) {
                        acc[r][j * 4 + 0] += a * b[j].x;
                        acc[r][j * 4 + 1] += a * b[j].y;
                        acc[r][j * 4 + 2] += a * b[j].z;
                        acc[r][j * 4 + 3] += a * b[j].w;
                    }
                }
            }
        }
        __syncthreads();          // Bs reads done before next pfStore
    }
    #pragma unroll
    for (int r = 0; r < 2; ++r) {
        size_t ob = (size_t)(rowBase + r0 + r) * 576 + 256;
        #pragma unroll
        for (int j = 0; j < 4; ++j)
            *(float4*)&out[ob + c0 + j * 64] =
                make_float4(acc[r][j * 4 + 0], acc[r][j * 4 + 1],
                            acc[r][j * 4 + 2], acc[r][j * 4 + 3]);
    }

    // ---- feat = agg2 @ Wn2L (K=64), 2 chunks, prefetched ----
    pfStore();                      // WN2L chunk 0 (loop-final barrier covers prior Bs reads)
    pfLoad(ws + WN2L_O + 2048);     // chunk 1 in flight
    {   // restage aS with agg2 (inter's aS reads done at loop-final barrier)
        const float4* s2 = (const float4*)(ws + AG2_O + (size_t)rowBase * 64);
        #pragma unroll
        for (int o = t; o < 512; o += TPB) {
            int row = o >> 4, c4 = o & 15;
            *(float4*)&aS[row * 68 + c4 * 4] = s2[o];
        }
    }
    float fa[2][4];
    #pragma unroll
    for (int r = 0; r < 2; ++r)
        #pragma unroll
        for (int c = 0; c < 4; ++c) fa[r][c] = 0.f;
    for (int kh = 0; kh < 2; ++kh) {
        __syncthreads();            // Bs + aS stores visible / prior reads done
        if (kh == 1) { pfStore(); __syncthreads(); }
        #pragma unroll
        for (int kq = 0; kq < 8; ++kq) {
            float av[2][4];
            #pragma unroll
            for (int r = 0; r < 2; ++r) {
                float4 a4 = *(const float4*)&aS[(r0 + r) * 68 + kh * 32 + kq * 4];
                av[r][0] = a4.x; av[r][1] = a4.y; av[r][2] = a4.z; av[r][3] = a4.w;
            }
            #pragma unroll
            for (int kk = 0; kk < 4; ++kk) {
                float4 b = *(const float4*)&Bs[(kq * 4 + kk) * 64 + c0];
                #pragma unroll
                for (int r = 0; r < 2; ++r) {
                    float a = av[r][kk];
                    fa[r][0] += a * b.x; fa[r][1] += a * b.y;
                    fa[r][2] += a * b.z; fa[r][3] += a * b.w;
                }
            }
        }
    }
    #pragma unroll
    for (int r = 0; r < 2; ++r)
        *(float4*)&out[(size_t)(rowBase + r0 + r) * 576 + 512 + c0] =
            make_float4(fa[r][0], fa[r][1], fa[r][2], fa[r][3]);
}

extern "C" void kernel_launch(void* const* d_in, const int* in_sizes, int n_in,
                              void* d_out, int out_size, void* d_ws, size_t ws_size,
                              hipStream_t stream) {
    (void)in_sizes; (void)n_in; (void)out_size; (void)ws_size;
    const float* in     = (const float*)d_in[0];
    const float* W_in   = (const float*)d_in[1];
    const float* b_in   = (const float*)d_in[2];
    const float* W_pos  = (const float*)d_in[3];
    const float* b_pos  = (const float*)d_in[4];
    const float* W_fc2  = (const float*)d_in[5];
    const float* b_fc2  = (const float*)d_in[6];
    const float* W_fc3  = (const float*)d_in[7];
    const float* b_fc3  = (const float*)d_in[8];
    const float* Wh1    = (const float*)d_in[9];
    const float* We1    = (const float*)d_in[10];
    const float* Wn1    = (const float*)d_in[11];
    const float* Wh2    = (const float*)d_in[12];
    const float* We2    = (const float*)d_in[13];
    const float* Wn2    = (const float*)d_in[14];
    const float* W_line = (const float*)d_in[15];
    float* out = (float*)d_out;
    float* ws  = (float*)d_ws;

    k_preA<<<1296, TPB, 0, stream>>>(W_in, b_in, W_pos, b_pos, Wn2, W_line,
                                     W_fc3, b_fc3, Wh1, Wh2, ws);
    k_preC<<<264, TPB, 0, stream>>>(W_fc2, b_fc2, ws);
    k_preD<<<516, TPB, 0, stream>>>(W_fc3, b_fc3, ws);
    k_main<<<R_ / 22, TPM, 0, stream>>>(in, We1, We2, ws, out);
    k_tail<<<R_ / 32, TPB, 0, stream>>>(Wn1, ws, out);
}